// Round 1
// baseline (844.023 us; speedup 1.0000x reference)
//
#include <hip/hip_runtime.h>
#include <math.h>

// Problem constants (from reference setup)
#define BQ    4      // batch B
#define LQ    2048   // L
#define D_DIM 1024   // D = H*HD
#define NQ    2048   // N descriptors
#define SMAX  1024   // padded per-batch window length (actual len_b ~ 512+-128)
#define TOPK  8

constexpr int BM = 64, BN = 64, BK = 16;

// ---------------------------------------------------------------------------
// q_ptrs may arrive as int64 (x64 enabled) or int32 (JAX default). q_ptrs[0]
// is always 0; if the second 32-bit word is also 0 it's the high half of an
// int64 -> int64 layout. Normalize to int32[BQ+1] in workspace.
__global__ void k_convert_qptrs(const int* __restrict__ q_raw, int* __restrict__ q_out) {
    if (threadIdx.x == 0 && blockIdx.x == 0) {
        bool is64 = (q_raw[1] == 0);
        for (int i = 0; i <= BQ; ++i)
            q_out[i] = is64 ? q_raw[2 * i] : q_raw[i];
    }
}

// ---------------------------------------------------------------------------
// C[m][n] = sum_k A[m][k] * W[n][k] + bias[n]   ("NT": both K-contiguous)
// 64x64 tile, 256 threads, 4x4 per thread, BK=16, float4 global loads.
__global__ __launch_bounds__(256) void k_gemm_nt_bias(
    const float* __restrict__ A, const float* __restrict__ W,
    const float* __restrict__ bias, float* __restrict__ C,
    int M, int N, int K)
{
    __shared__ float As[BK][BM];
    __shared__ float Ws[BK][BN];
    const int tid = threadIdx.x;
    const int tx = tid & 15;        // n sub-tile
    const int ty = tid >> 4;        // m sub-tile
    const int bm = blockIdx.y * BM;
    const int bn = blockIdx.x * BN;
    const int lr = tid >> 2;        // load row (0..63)
    const int lc = (tid & 3) * 4;   // load col (0,4,8,12)

    const float* Ap = A + (size_t)(bm + lr) * K + lc;
    const float* Wp = W + (size_t)(bn + lr) * K + lc;

    float acc[4][4] = {};

    for (int k0 = 0; k0 < K; k0 += BK) {
        float4 a = *reinterpret_cast<const float4*>(Ap + k0);
        float4 w = *reinterpret_cast<const float4*>(Wp + k0);
        __syncthreads();
        As[lc + 0][lr] = a.x; As[lc + 1][lr] = a.y;
        As[lc + 2][lr] = a.z; As[lc + 3][lr] = a.w;
        Ws[lc + 0][lr] = w.x; Ws[lc + 1][lr] = w.y;
        Ws[lc + 2][lr] = w.z; Ws[lc + 3][lr] = w.w;
        __syncthreads();
#pragma unroll
        for (int k = 0; k < BK; ++k) {
            float4 av = *reinterpret_cast<const float4*>(&As[k][ty * 4]);
            float4 wv = *reinterpret_cast<const float4*>(&Ws[k][tx * 4]);
            const float am[4] = {av.x, av.y, av.z, av.w};
            const float wn[4] = {wv.x, wv.y, wv.z, wv.w};
#pragma unroll
            for (int i = 0; i < 4; ++i)
#pragma unroll
                for (int j = 0; j < 4; ++j)
                    acc[i][j] = fmaf(am[i], wn[j], acc[i][j]);
        }
    }
    float bj[4];
#pragma unroll
    for (int j = 0; j < 4; ++j) bj[j] = bias ? bias[bn + tx * 4 + j] : 0.f;
#pragma unroll
    for (int i = 0; i < 4; ++i) {
        size_t r = (size_t)(bm + ty * 4 + i) * N + bn + tx * 4;
#pragma unroll
        for (int j = 0; j < 4; ++j)
            C[r + j] = acc[i][j] + bj[j];
    }
}

// ---------------------------------------------------------------------------
// logits[b][l][s] = Tproj[b*L+l] . Dall[start_b + s]  for s < len_b
// Same tiling as the GEMM. Blocks with s-tile fully past len_b exit early.
// Rows past N-1 are clamped (their results are never read: consumer masks
// s >= len_b).
__global__ __launch_bounds__(256) void k_logits(
    const float* __restrict__ Tproj, const float* __restrict__ Dall,
    const int* __restrict__ qp, float* __restrict__ logits)
{
    const int b = blockIdx.z;
    const int start = qp[b];
    const int len = qp[b + 1] - start;
    const int bn = blockIdx.x * BN;   // s offset
    if (bn >= len) return;
    const int bm = blockIdx.y * BM;   // l offset

    __shared__ float As[BK][BM];
    __shared__ float Ws[BK][BN];
    const int tid = threadIdx.x;
    const int tx = tid & 15;
    const int ty = tid >> 4;
    const int lr = tid >> 2;
    const int lc = (tid & 3) * 4;

    const float* Ap = Tproj + ((size_t)b * LQ + bm + lr) * D_DIM + lc;
    int wrow = start + bn + lr; if (wrow > NQ - 1) wrow = NQ - 1;
    const float* Wp = Dall + (size_t)wrow * D_DIM + lc;

    float acc[4][4] = {};

    for (int k0 = 0; k0 < D_DIM; k0 += BK) {
        float4 a = *reinterpret_cast<const float4*>(Ap + k0);
        float4 w = *reinterpret_cast<const float4*>(Wp + k0);
        __syncthreads();
        As[lc + 0][lr] = a.x; As[lc + 1][lr] = a.y;
        As[lc + 2][lr] = a.z; As[lc + 3][lr] = a.w;
        Ws[lc + 0][lr] = w.x; Ws[lc + 1][lr] = w.y;
        Ws[lc + 2][lr] = w.z; Ws[lc + 3][lr] = w.w;
        __syncthreads();
#pragma unroll
        for (int k = 0; k < BK; ++k) {
            float4 av = *reinterpret_cast<const float4*>(&As[k][ty * 4]);
            float4 wv = *reinterpret_cast<const float4*>(&Ws[k][tx * 4]);
            const float am[4] = {av.x, av.y, av.z, av.w};
            const float wn[4] = {wv.x, wv.y, wv.z, wv.w};
#pragma unroll
            for (int i = 0; i < 4; ++i)
#pragma unroll
                for (int j = 0; j < 4; ++j)
                    acc[i][j] = fmaf(am[i], wn[j], acc[i][j]);
        }
    }
#pragma unroll
    for (int i = 0; i < 4; ++i) {
        size_t r = ((size_t)b * LQ + bm + ty * 4 + i) * SMAX + bn + tx * 4;
#pragma unroll
        for (int j = 0; j < 4; ++j)
            logits[r + j] = acc[i][j];
    }
}

// ---------------------------------------------------------------------------
// Per (b,l): top-8 over logits[b][l][0:len], softmax over the 8, then
// mix[b*L+l][:] = sum_k gate_k * Z[start + s_k][:]
__global__ __launch_bounds__(256) void k_topk_mix(
    const float* __restrict__ logits, const float* __restrict__ Z,
    const int* __restrict__ qp, float* __restrict__ mix)
{
    const int b = blockIdx.y, l = blockIdx.x;
    const int start = qp[b];
    const int len = qp[b + 1] - start;
    const int tid = threadIdx.x;

    __shared__ float sl[SMAX];
    __shared__ float svals[TOPK];
    __shared__ int   sidx[TOPK];
    __shared__ float wv[4];
    __shared__ int   wi[4];

    const float* row = logits + ((size_t)b * LQ + l) * SMAX;
    for (int s = tid; s < len; s += 256) sl[s] = row[s];
    __syncthreads();

    for (int it = 0; it < TOPK; ++it) {
        float best = -INFINITY; int bi = -1;
        for (int s = tid; s < len; s += 256) {
            float v = sl[s];
            if (v > best) { best = v; bi = s; }   // strict > keeps lowest idx
        }
#pragma unroll
        for (int off = 32; off > 0; off >>= 1) {
            float ov = __shfl_down(best, off);
            int   oi = __shfl_down(bi, off);
            if (ov > best || (ov == best && oi >= 0 && (bi < 0 || oi < bi))) {
                best = ov; bi = oi;
            }
        }
        if ((tid & 63) == 0) { wv[tid >> 6] = best; wi[tid >> 6] = bi; }
        __syncthreads();
        if (tid == 0) {
#pragma unroll
            for (int w2 = 1; w2 < 4; ++w2) {
                if (wv[w2] > best ||
                    (wv[w2] == best && wi[w2] >= 0 && (bi < 0 || wi[w2] < bi))) {
                    best = wv[w2]; bi = wi[w2];
                }
            }
            svals[it] = best; sidx[it] = bi;
            if (bi >= 0) sl[bi] = -INFINITY;      // remove from next rounds
        }
        __syncthreads();
    }

    // softmax over the 8 picked values (svals[0] is the max)
    float m = svals[0];
    float g[TOPK]; float denom = 0.f;
#pragma unroll
    for (int k = 0; k < TOPK; ++k) { g[k] = expf(svals[k] - m); denom += g[k]; }
    float inv = 1.f / denom;

    const float* zr[TOPK];
#pragma unroll
    for (int k = 0; k < TOPK; ++k) {
        int si = sidx[k] >= 0 ? sidx[k] : 0;      // guard (len >= TOPK+1 by construction)
        zr[k] = Z + (size_t)(start + si) * D_DIM;
    }
    float* mrow = mix + ((size_t)b * LQ + l) * D_DIM;
    for (int d = tid; d < D_DIM; d += 256) {
        float acc = 0.f;
#pragma unroll
        for (int k = 0; k < TOPK; ++k) acc = fmaf(g[k] * inv, zr[k][d], acc);
        mrow[d] = acc;
    }
}

// ---------------------------------------------------------------------------
extern "C" void kernel_launch(void* const* d_in, const int* in_sizes, int n_in,
                              void* d_out, int out_size, void* d_ws, size_t ws_size,
                              hipStream_t stream) {
    const float* token_states = (const float*)d_in[0];
    const float* Z_sets       = (const float*)d_in[1];
    const float* desc_q       = (const float*)d_in[2];
    const int*   q_raw        = (const int*)d_in[3];
    const float* Wg_w = (const float*)d_in[4];
    const float* Wg_b = (const float*)d_in[5];
    const float* Wd_w = (const float*)d_in[6];
    const float* Wd_b = (const float*)d_in[7];
    const float* out_w = (const float*)d_in[8];
    const float* out_b = (const float*)d_in[9];
    float* out = (float*)d_out;

    char* ws = (char*)d_ws;
    int*   qp     = (int*)ws;                                   // 256 B slot
    float* Tproj  = (float*)(ws + 256);                         // 8192x1024 f32
    float* Dall   = Tproj + (size_t)BQ * LQ * D_DIM;            // 2048x1024 f32
    float* logit  = Dall + (size_t)NQ * D_DIM;                  // 8192x1024 f32
    float* mix    = logit + (size_t)BQ * LQ * SMAX;             // 8192x1024 f32

    k_convert_qptrs<<<1, 64, 0, stream>>>(q_raw, qp);

    // Tproj = token_states @ Wg_w^T + Wg_b
    k_gemm_nt_bias<<<dim3(D_DIM / BN, (BQ * LQ) / BM), 256, 0, stream>>>(
        token_states, Wg_w, Wg_b, Tproj, BQ * LQ, D_DIM, D_DIM);

    // Dall = desc_q @ Wd_w^T + Wd_b
    k_gemm_nt_bias<<<dim3(D_DIM / BN, NQ / BM), 256, 0, stream>>>(
        desc_q, Wd_w, Wd_b, Dall, NQ, D_DIM, D_DIM);

    // logits (per batch window)
    k_logits<<<dim3(SMAX / BN, LQ / BM, BQ), 256, 0, stream>>>(
        Tproj, Dall, qp, logit);

    // top-8 + softmax + Z gather
    k_topk_mix<<<dim3(LQ, BQ), 256, 0, stream>>>(logit, Z_sets, qp, mix);

    // out = mix @ out_w^T + out_b
    k_gemm_nt_bias<<<dim3(D_DIM / BN, (BQ * LQ) / BM), 256, 0, stream>>>(
        mix, out_w, out_b, out, BQ * LQ, D_DIM, D_DIM);
}

// Round 3
// 273.142 us; speedup vs baseline: 3.0901x; 3.0901x over previous
//
#include <hip/hip_runtime.h>
#include <hip/hip_bf16.h>
#include <math.h>

#define BQ    4
#define LQ    2048
#define D_DIM 1024
#define NQ    2048
#define SMAX  1024
#define TOPK  8

typedef __attribute__((ext_vector_type(8))) short          short8;
typedef __attribute__((ext_vector_type(4))) float          f32x4;
typedef __attribute__((ext_vector_type(8))) unsigned short ushort8;
typedef __attribute__((ext_vector_type(4))) unsigned short ushort4v;

typedef __attribute__((address_space(3))) void as3_void;
typedef __attribute__((address_space(1))) void as1_void;

__device__ __forceinline__ void gload_lds16(const void* g, void* l) {
    __builtin_amdgcn_global_load_lds((const as1_void*)g, (as3_void*)l, 16, 0, 0);
}

__device__ __forceinline__ unsigned short f2bf(float f) {
    __hip_bfloat16 h = __float2bfloat16(f);
    return *reinterpret_cast<unsigned short*>(&h);
}
__device__ __forceinline__ float bf2f(unsigned short u) {
    __hip_bfloat16 h = *reinterpret_cast<__hip_bfloat16*>(&u);
    return __bfloat162float(h);
}

// ---------------------------------------------------------------------------
__global__ void k_convert_qptrs(const int* __restrict__ q_raw, int* __restrict__ q_out) {
    if (threadIdx.x == 0 && blockIdx.x == 0) {
        bool is64 = (q_raw[1] == 0);
        for (int i = 0; i <= BQ; ++i)
            q_out[i] = is64 ? q_raw[2 * i] : q_raw[i];
    }
}

// fp32 -> bf16 plain (for out_w)
__global__ __launch_bounds__(256) void k_cvt_bf16(
    const float* __restrict__ in, unsigned short* __restrict__ out, int n)
{
    int i = (blockIdx.x * 256 + threadIdx.x) * 8;
    if (i >= n) return;
    float4 v0 = *reinterpret_cast<const float4*>(in + i);
    float4 v1 = *reinterpret_cast<const float4*>(in + i + 4);
    ushort8 u;
    u[0] = f2bf(v0.x); u[1] = f2bf(v0.y); u[2] = f2bf(v0.z); u[3] = f2bf(v0.w);
    u[4] = f2bf(v1.x); u[5] = f2bf(v1.y); u[6] = f2bf(v1.z); u[7] = f2bf(v1.w);
    *reinterpret_cast<ushort8*>(out + i) = u;
}

// fp32 -> (hi, lo) bf16 split: x ~= hi + lo, residual rel ~2^-17
__global__ __launch_bounds__(256) void k_cvt_split(
    const float* __restrict__ in, unsigned short* __restrict__ hi,
    unsigned short* __restrict__ lo, int n)
{
    int i = (blockIdx.x * 256 + threadIdx.x) * 8;
    if (i >= n) return;
    float4 v0 = *reinterpret_cast<const float4*>(in + i);
    float4 v1 = *reinterpret_cast<const float4*>(in + i + 4);
    float x[8] = {v0.x, v0.y, v0.z, v0.w, v1.x, v1.y, v1.z, v1.w};
    ushort8 h8, l8;
#pragma unroll
    for (int k = 0; k < 8; ++k) {
        unsigned short h = f2bf(x[k]);
        h8[k] = h;
        l8[k] = f2bf(x[k] - bf2f(h));
    }
    *reinterpret_cast<ushort8*>(hi + i) = h8;
    *reinterpret_cast<ushort8*>(lo + i) = l8;
}

// ---------------------------------------------------------------------------
// Split-bf16 GEMM (3-MFMA fp32 emulation):
//   C = (Ah+Al) @ (Wh+Wl)^T + bias ~= AhWh + AhWl + AlWh  (AlWl ~ 2^-17, dropped)
// 128x128 tile, BK=32, 4 waves, mfma_f32_16x16x32_bf16, slot-XOR LDS swizzle.
// Output: hi/lo bf16 plane pair.
__global__ __launch_bounds__(256) void k_gemm_split(
    const unsigned short* __restrict__ Ah, const unsigned short* __restrict__ Al,
    const unsigned short* __restrict__ Wh, const unsigned short* __restrict__ Wl,
    const float* __restrict__ bias,
    unsigned short* __restrict__ Ch, unsigned short* __restrict__ Cl,
    int M, int N, int K)
{
    __shared__ __align__(16) char AsH[8192], AsL[8192], BsH[8192], BsL[8192];

    const int tid = threadIdx.x;
    const int ln  = tid & 63;
    const int wid = tid >> 6;
    const int wm  = wid >> 1, wn = wid & 1;
    const int fr  = ln & 15, fs = ln >> 4;
    const int brow = blockIdx.y * 128;
    const int bcol = blockIdx.x * 128;
    const int st   = ln & 3;

    f32x4 acc[4][4] = {};

    for (int k0 = 0; k0 < K; k0 += 32) {
        if (k0) __syncthreads();
#pragma unroll
        for (int i = 0; i < 2; ++i) {
            int r  = wid * 32 + i * 16 + (ln >> 2);
            int kk = (st ^ (r & 3)) * 8;
            size_t offA = (size_t)(brow + r) * K + k0 + kk;
            size_t offW = (size_t)(bcol + r) * K + k0 + kk;
            int ldsOff = (wid * 2 + i) * 1024;
            gload_lds16(Ah + offA, AsH + ldsOff);
            gload_lds16(Al + offA, AsL + ldsOff);
            gload_lds16(Wh + offW, BsH + ldsOff);
            gload_lds16(Wl + offW, BsL + ldsOff);
        }
        __syncthreads();

        short8 ah[4], al[4], bh[4], bl[4];
#pragma unroll
        for (int mi = 0; mi < 4; ++mi) {
            int r = wm * 64 + mi * 16 + fr;
            int o = r * 64 + ((fs ^ (r & 3)) << 4);
            ah[mi] = *reinterpret_cast<const short8*>(AsH + o);
            al[mi] = *reinterpret_cast<const short8*>(AsL + o);
        }
#pragma unroll
        for (int ni = 0; ni < 4; ++ni) {
            int c = wn * 64 + ni * 16 + fr;
            int o = c * 64 + ((fs ^ (c & 3)) << 4);
            bh[ni] = *reinterpret_cast<const short8*>(BsH + o);
            bl[ni] = *reinterpret_cast<const short8*>(BsL + o);
        }
#pragma unroll
        for (int mi = 0; mi < 4; ++mi)
#pragma unroll
            for (int ni = 0; ni < 4; ++ni)
                acc[mi][ni] = __builtin_amdgcn_mfma_f32_16x16x32_bf16(
                    ah[mi], bh[ni], acc[mi][ni], 0, 0, 0);
#pragma unroll
        for (int mi = 0; mi < 4; ++mi)
#pragma unroll
            for (int ni = 0; ni < 4; ++ni)
                acc[mi][ni] = __builtin_amdgcn_mfma_f32_16x16x32_bf16(
                    ah[mi], bl[ni], acc[mi][ni], 0, 0, 0);
#pragma unroll
        for (int mi = 0; mi < 4; ++mi)
#pragma unroll
            for (int ni = 0; ni < 4; ++ni)
                acc[mi][ni] = __builtin_amdgcn_mfma_f32_16x16x32_bf16(
                    al[mi], bh[ni], acc[mi][ni], 0, 0, 0);
    }

    float bv[4];
#pragma unroll
    for (int ni = 0; ni < 4; ++ni)
        bv[ni] = bias ? bias[bcol + wn * 64 + ni * 16 + fr] : 0.f;

#pragma unroll
    for (int mi = 0; mi < 4; ++mi) {
#pragma unroll
        for (int reg = 0; reg < 4; ++reg) {
            int row = brow + wm * 64 + mi * 16 + fs * 4 + reg;
#pragma unroll
            for (int ni = 0; ni < 4; ++ni) {
                int col = bcol + wn * 64 + ni * 16 + fr;
                float v = acc[mi][ni][reg] + bv[ni];
                unsigned short h = f2bf(v);
                Ch[(size_t)row * N + col] = h;
                Cl[(size_t)row * N + col] = f2bf(v - bf2f(h));
            }
        }
    }
}

// ---------------------------------------------------------------------------
// Windowed split-bf16 logits: logits[b][l][s] = T[b*L+l] . D[start_b+s], fp32.
__global__ __launch_bounds__(256) void k_logits_split(
    const unsigned short* __restrict__ Th, const unsigned short* __restrict__ Tl,
    const unsigned short* __restrict__ Dh, const unsigned short* __restrict__ Dl,
    const int* __restrict__ qp, float* __restrict__ logits)
{
    const int b = blockIdx.z;
    const int start = qp[b], len = qp[b + 1] - start;
    const int bcol = blockIdx.x * 128;
    if (bcol >= len) return;
    const int brow = blockIdx.y * 128;

    __shared__ __align__(16) char AsH[8192], AsL[8192], BsH[8192], BsL[8192];

    const int tid = threadIdx.x;
    const int ln  = tid & 63;
    const int wid = tid >> 6;
    const int wm  = wid >> 1, wn = wid & 1;
    const int fr  = ln & 15, fs = ln >> 4;
    const int st  = ln & 3;

    const size_t abase = (size_t)b * LQ;

    f32x4 acc[4][4] = {};

    for (int k0 = 0; k0 < D_DIM; k0 += 32) {
        if (k0) __syncthreads();
#pragma unroll
        for (int i = 0; i < 2; ++i) {
            int r  = wid * 32 + i * 16 + (ln >> 2);
            int kk = (st ^ (r & 3)) * 8;
            size_t offA = (abase + brow + r) * D_DIM + k0 + kk;
            int wr = start + bcol + r; if (wr > NQ - 1) wr = NQ - 1;
            size_t offW = (size_t)wr * D_DIM + k0 + kk;
            int ldsOff = (wid * 2 + i) * 1024;
            gload_lds16(Th + offA, AsH + ldsOff);
            gload_lds16(Tl + offA, AsL + ldsOff);
            gload_lds16(Dh + offW, BsH + ldsOff);
            gload_lds16(Dl + offW, BsL + ldsOff);
        }
        __syncthreads();

        short8 ah[4], al[4], bh[4], bl[4];
#pragma unroll
        for (int mi = 0; mi < 4; ++mi) {
            int r = wm * 64 + mi * 16 + fr;
            int o = r * 64 + ((fs ^ (r & 3)) << 4);
            ah[mi] = *reinterpret_cast<const short8*>(AsH + o);
            al[mi] = *reinterpret_cast<const short8*>(AsL + o);
        }
#pragma unroll
        for (int ni = 0; ni < 4; ++ni) {
            int c = wn * 64 + ni * 16 + fr;
            int o = c * 64 + ((fs ^ (c & 3)) << 4);
            bh[ni] = *reinterpret_cast<const short8*>(BsH + o);
            bl[ni] = *reinterpret_cast<const short8*>(BsL + o);
        }
#pragma unroll
        for (int mi = 0; mi < 4; ++mi)
#pragma unroll
            for (int ni = 0; ni < 4; ++ni)
                acc[mi][ni] = __builtin_amdgcn_mfma_f32_16x16x32_bf16(
                    ah[mi], bh[ni], acc[mi][ni], 0, 0, 0);
#pragma unroll
        for (int mi = 0; mi < 4; ++mi)
#pragma unroll
            for (int ni = 0; ni < 4; ++ni)
                acc[mi][ni] = __builtin_amdgcn_mfma_f32_16x16x32_bf16(
                    ah[mi], bl[ni], acc[mi][ni], 0, 0, 0);
#pragma unroll
        for (int mi = 0; mi < 4; ++mi)
#pragma unroll
            for (int ni = 0; ni < 4; ++ni)
                acc[mi][ni] = __builtin_amdgcn_mfma_f32_16x16x32_bf16(
                    al[mi], bh[ni], acc[mi][ni], 0, 0, 0);
    }

#pragma unroll
    for (int mi = 0; mi < 4; ++mi) {
#pragma unroll
        for (int reg = 0; reg < 4; ++reg) {
            size_t row = (size_t)b * LQ + brow + wm * 64 + mi * 16 + fs * 4 + reg;
#pragma unroll
            for (int ni = 0; ni < 4; ++ni) {
                int col = bcol + wn * 64 + ni * 16 + fr;
                logits[row * SMAX + col] = acc[mi][ni][reg];
            }
        }
    }
}

// ---------------------------------------------------------------------------
// Plain bf16 GEMM, fp32 out (final projection; bf16 accuracy is sufficient).
__global__ __launch_bounds__(256) void k_gemm_bf16_f32out(
    const unsigned short* __restrict__ A, const unsigned short* __restrict__ W,
    const float* __restrict__ bias, float* __restrict__ C,
    int M, int N, int K)
{
    __shared__ __align__(16) char As[8192], Bs[8192];

    const int tid = threadIdx.x;
    const int ln  = tid & 63;
    const int wid = tid >> 6;
    const int wm  = wid >> 1, wn = wid & 1;
    const int fr  = ln & 15, fs = ln >> 4;
    const int brow = blockIdx.y * 128;
    const int bcol = blockIdx.x * 128;
    const int st   = ln & 3;

    f32x4 acc[4][4] = {};

    for (int k0 = 0; k0 < K; k0 += 32) {
        if (k0) __syncthreads();
#pragma unroll
        for (int i = 0; i < 2; ++i) {
            int r  = wid * 32 + i * 16 + (ln >> 2);
            int kk = (st ^ (r & 3)) * 8;
            gload_lds16(A + (size_t)(brow + r) * K + k0 + kk, As + (wid * 2 + i) * 1024);
            gload_lds16(W + (size_t)(bcol + r) * K + k0 + kk, Bs + (wid * 2 + i) * 1024);
        }
        __syncthreads();

        short8 a[4], b[4];
#pragma unroll
        for (int mi = 0; mi < 4; ++mi) {
            int r = wm * 64 + mi * 16 + fr;
            a[mi] = *reinterpret_cast<const short8*>(As + r * 64 + ((fs ^ (r & 3)) << 4));
        }
#pragma unroll
        for (int ni = 0; ni < 4; ++ni) {
            int c = wn * 64 + ni * 16 + fr;
            b[ni] = *reinterpret_cast<const short8*>(Bs + c * 64 + ((fs ^ (c & 3)) << 4));
        }
#pragma unroll
        for (int mi = 0; mi < 4; ++mi)
#pragma unroll
            for (int ni = 0; ni < 4; ++ni)
                acc[mi][ni] = __builtin_amdgcn_mfma_f32_16x16x32_bf16(
                    a[mi], b[ni], acc[mi][ni], 0, 0, 0);
    }

    float bv[4];
#pragma unroll
    for (int ni = 0; ni < 4; ++ni)
        bv[ni] = bias ? bias[bcol + wn * 64 + ni * 16 + fr] : 0.f;

#pragma unroll
    for (int mi = 0; mi < 4; ++mi) {
#pragma unroll
        for (int reg = 0; reg < 4; ++reg) {
            int row = brow + wm * 64 + mi * 16 + fs * 4 + reg;
#pragma unroll
            for (int ni = 0; ni < 4; ++ni) {
                int col = bcol + wn * 64 + ni * 16 + fr;
                C[(size_t)row * N + col] = acc[mi][ni][reg] + bv[ni];
            }
        }
    }
}

// ---------------------------------------------------------------------------
// Per (b,l): top-8 over logits[b][l][0:len], softmax, mix (bf16 out).
__global__ __launch_bounds__(256) void k_topk_mix(
    const float* __restrict__ logits, const float* __restrict__ Z,
    const int* __restrict__ qp, unsigned short* __restrict__ mix)
{
    const int b = blockIdx.y, l = blockIdx.x;
    const int start = qp[b];
    const int len = qp[b + 1] - start;
    const int tid = threadIdx.x;

    __shared__ float sl[SMAX];
    __shared__ float svals[TOPK];
    __shared__ int   sidx[TOPK];
    __shared__ float wv[4];
    __shared__ int   wi[4];

    const float* row = logits + ((size_t)b * LQ + l) * SMAX;
    for (int s = tid; s < len; s += 256) sl[s] = row[s];
    __syncthreads();

    for (int it = 0; it < TOPK; ++it) {
        float best = -INFINITY; int bi = -1;
        for (int s = tid; s < len; s += 256) {
            float v = sl[s];
            if (v > best) { best = v; bi = s; }
        }
#pragma unroll
        for (int off = 32; off > 0; off >>= 1) {
            float ov = __shfl_down(best, off);
            int   oi = __shfl_down(bi, off);
            if (ov > best || (ov == best && oi >= 0 && (bi < 0 || oi < bi))) {
                best = ov; bi = oi;
            }
        }
        if ((tid & 63) == 0) { wv[tid >> 6] = best; wi[tid >> 6] = bi; }
        __syncthreads();
        if (tid == 0) {
#pragma unroll
            for (int w2 = 1; w2 < 4; ++w2) {
                if (wv[w2] > best ||
                    (wv[w2] == best && wi[w2] >= 0 && (bi < 0 || wi[w2] < bi))) {
                    best = wv[w2]; bi = wi[w2];
                }
            }
            svals[it] = best; sidx[it] = bi;
            if (bi >= 0) sl[bi] = -INFINITY;
        }
        __syncthreads();
    }

    float m = svals[0];
    float g[TOPK]; float denom = 0.f;
#pragma unroll
    for (int k = 0; k < TOPK; ++k) { g[k] = expf(svals[k] - m); denom += g[k]; }
    float inv = 1.f / denom;

    const float* zr[TOPK];
#pragma unroll
    for (int k = 0; k < TOPK; ++k) {
        int si = sidx[k] >= 0 ? sidx[k] : 0;
        zr[k] = Z + (size_t)(start + si) * D_DIM;
    }
    unsigned short* mrow = mix + ((size_t)b * LQ + l) * D_DIM;
    {
        int d4 = tid;   // D_DIM/4 == 256 == blockDim
        float ax = 0.f, ay = 0.f, az = 0.f, aw = 0.f;
#pragma unroll
        for (int k = 0; k < TOPK; ++k) {
            float wgt = g[k] * inv;
            float4 z = reinterpret_cast<const float4*>(zr[k])[d4];
            ax = fmaf(wgt, z.x, ax); ay = fmaf(wgt, z.y, ay);
            az = fmaf(wgt, z.z, az); aw = fmaf(wgt, z.w, aw);
        }
        ushort4v o;
        o[0] = f2bf(ax); o[1] = f2bf(ay); o[2] = f2bf(az); o[3] = f2bf(aw);
        *reinterpret_cast<ushort4v*>(mrow + d4 * 4) = o;
    }
}

// ---------------------------------------------------------------------------
extern "C" void kernel_launch(void* const* d_in, const int* in_sizes, int n_in,
                              void* d_out, int out_size, void* d_ws, size_t ws_size,
                              hipStream_t stream) {
    const float* token_states = (const float*)d_in[0];
    const float* Z_sets       = (const float*)d_in[1];
    const float* desc_q       = (const float*)d_in[2];
    const int*   q_raw        = (const int*)d_in[3];
    const float* Wg_w  = (const float*)d_in[4];
    const float* Wg_b  = (const float*)d_in[5];
    const float* Wd_w  = (const float*)d_in[6];
    const float* Wd_b  = (const float*)d_in[7];
    const float* out_w = (const float*)d_in[8];
    const float* out_b = (const float*)d_in[9];
    float* out = (float*)d_out;

    const size_t NTOK = (size_t)BQ * LQ * D_DIM;   // 8388608
    const size_t NDES = (size_t)NQ * D_DIM;        // 2097152
    const size_t NW   = (size_t)D_DIM * D_DIM;     // 1048576

    char* ws = (char*)d_ws;
    int* qp = (int*)ws;
    unsigned short* tokenH = (unsigned short*)(ws + 256);
    unsigned short* tokenL = tokenH + NTOK;
    unsigned short* descH  = tokenL + NTOK;
    unsigned short* descL  = descH + NDES;
    unsigned short* wgH    = descL + NDES;
    unsigned short* wgL    = wgH + NW;
    unsigned short* wdH    = wgL + NW;
    unsigned short* wdL    = wdH + NW;
    unsigned short* owb    = wdL + NW;
    unsigned short* TprojH = owb + NW;
    unsigned short* TprojL = TprojH + NTOK;
    unsigned short* DprojH = TprojL + NTOK;
    unsigned short* DprojL = DprojH + NDES;
    // Aliases (lifetimes disjoint on the serial stream):
    float* logit          = (float*)tokenH;          // 33.5 MB over token planes (dead after Tproj GEMM)
    unsigned short* mixb  = TprojH;                  // 16.8 MB over TprojH (dead after logits GEMM)

    k_convert_qptrs<<<1, 64, 0, stream>>>(q_raw, qp);

    k_cvt_split<<<NTOK / 2048, 256, 0, stream>>>(token_states, tokenH, tokenL, (int)NTOK);
    k_cvt_split<<<NDES / 2048, 256, 0, stream>>>(desc_q, descH, descL, (int)NDES);
    k_cvt_split<<<NW / 2048, 256, 0, stream>>>(Wg_w, wgH, wgL, (int)NW);
    k_cvt_split<<<NW / 2048, 256, 0, stream>>>(Wd_w, wdH, wdL, (int)NW);
    k_cvt_bf16<<<NW / 2048, 256, 0, stream>>>(out_w, owb, (int)NW);

    // Tproj = token @ Wg^T + b  (split out)
    k_gemm_split<<<dim3(D_DIM / 128, (BQ * LQ) / 128), 256, 0, stream>>>(
        tokenH, tokenL, wgH, wgL, Wg_b, TprojH, TprojL, BQ * LQ, D_DIM, D_DIM);

    // Dproj = desc @ Wd^T + b  (split out)
    k_gemm_split<<<dim3(D_DIM / 128, NQ / 128), 256, 0, stream>>>(
        descH, descL, wdH, wdL, Wd_b, DprojH, DprojL, NQ, D_DIM, D_DIM);

    // logits (fp32, windowed; overwrites token planes)
    k_logits_split<<<dim3(SMAX / 128, LQ / 128, BQ), 256, 0, stream>>>(
        TprojH, TprojL, DprojH, DprojL, qp, logit);

    // top-8 + softmax + Z mix (bf16; overwrites TprojH)
    k_topk_mix<<<dim3(LQ, BQ), 256, 0, stream>>>(logit, Z_sets, qp, mixb);

    // out = mix @ out_w^T + b (fp32)
    k_gemm_bf16_f32out<<<dim3(D_DIM / 128, (BQ * LQ) / 128), 256, 0, stream>>>(
        mixb, owb, out_b, out, BQ * LQ, D_DIM, D_DIM);
}

// Round 4
// 247.349 us; speedup vs baseline: 3.4123x; 1.1043x over previous
//
#include <hip/hip_runtime.h>
#include <hip/hip_bf16.h>
#include <math.h>

#define BQ    4
#define LQ    2048
#define D_DIM 1024
#define NQ    2048
#define SMAX  1024
#define TOPK  8

typedef __attribute__((ext_vector_type(8))) short          short8;
typedef __attribute__((ext_vector_type(4))) float          f32x4;
typedef __attribute__((ext_vector_type(8))) unsigned short ushort8;
typedef __attribute__((ext_vector_type(4))) unsigned short ushort4v;

typedef __attribute__((address_space(3))) void as3_void;
typedef __attribute__((address_space(1))) void as1_void;

__device__ __forceinline__ void gload_lds16(const void* g, void* l) {
    __builtin_amdgcn_global_load_lds((const as1_void*)g, (as3_void*)l, 16, 0, 0);
}

__device__ __forceinline__ unsigned short f2bf(float f) {
    __hip_bfloat16 h = __float2bfloat16(f);
    return *reinterpret_cast<unsigned short*>(&h);
}
__device__ __forceinline__ float bf2f(unsigned short u) {
    __hip_bfloat16 h = *reinterpret_cast<__hip_bfloat16*>(&u);
    return __bfloat162float(h);
}

// ---------------------------------------------------------------------------
__global__ void k_convert_qptrs(const int* __restrict__ q_raw, int* __restrict__ q_out) {
    if (threadIdx.x == 0 && blockIdx.x == 0) {
        bool is64 = (q_raw[1] == 0);
        for (int i = 0; i <= BQ; ++i)
            q_out[i] = is64 ? q_raw[2 * i] : q_raw[i];
    }
}

__global__ __launch_bounds__(256) void k_cvt_bf16(
    const float* __restrict__ in, unsigned short* __restrict__ out, int n)
{
    int i = (blockIdx.x * 256 + threadIdx.x) * 8;
    if (i >= n) return;
    float4 v0 = *reinterpret_cast<const float4*>(in + i);
    float4 v1 = *reinterpret_cast<const float4*>(in + i + 4);
    ushort8 u;
    u[0] = f2bf(v0.x); u[1] = f2bf(v0.y); u[2] = f2bf(v0.z); u[3] = f2bf(v0.w);
    u[4] = f2bf(v1.x); u[5] = f2bf(v1.y); u[6] = f2bf(v1.z); u[7] = f2bf(v1.w);
    *reinterpret_cast<ushort8*>(out + i) = u;
}

__global__ __launch_bounds__(256) void k_cvt_split(
    const float* __restrict__ in, unsigned short* __restrict__ hi,
    unsigned short* __restrict__ lo, int n)
{
    int i = (blockIdx.x * 256 + threadIdx.x) * 8;
    if (i >= n) return;
    float4 v0 = *reinterpret_cast<const float4*>(in + i);
    float4 v1 = *reinterpret_cast<const float4*>(in + i + 4);
    float x[8] = {v0.x, v0.y, v0.z, v0.w, v1.x, v1.y, v1.z, v1.w};
    ushort8 h8, l8;
#pragma unroll
    for (int k = 0; k < 8; ++k) {
        unsigned short h = f2bf(x[k]);
        h8[k] = h;
        l8[k] = f2bf(x[k] - bf2f(h));
    }
    *reinterpret_cast<ushort8*>(hi + i) = h8;
    *reinterpret_cast<ushort8*>(lo + i) = l8;
}

// ---------------------------------------------------------------------------
// Split-bf16 GEMM (3-MFMA fp32 emulation), 128x128 tile, BK=32.
__global__ __launch_bounds__(256) void k_gemm_split(
    const unsigned short* __restrict__ Ah, const unsigned short* __restrict__ Al,
    const unsigned short* __restrict__ Wh, const unsigned short* __restrict__ Wl,
    const float* __restrict__ bias,
    unsigned short* __restrict__ Ch, unsigned short* __restrict__ Cl,
    int M, int N, int K)
{
    __shared__ __align__(16) char AsH[8192], AsL[8192], BsH[8192], BsL[8192];

    const int tid = threadIdx.x;
    const int ln  = tid & 63;
    const int wid = tid >> 6;
    const int wm  = wid >> 1, wn = wid & 1;
    const int fr  = ln & 15, fs = ln >> 4;
    const int brow = blockIdx.y * 128;
    const int bcol = blockIdx.x * 128;
    const int st   = ln & 3;

    f32x4 acc[4][4] = {};

    for (int k0 = 0; k0 < K; k0 += 32) {
        if (k0) __syncthreads();
#pragma unroll
        for (int i = 0; i < 2; ++i) {
            int r  = wid * 32 + i * 16 + (ln >> 2);
            int kk = (st ^ (r & 3)) * 8;
            size_t offA = (size_t)(brow + r) * K + k0 + kk;
            size_t offW = (size_t)(bcol + r) * K + k0 + kk;
            int ldsOff = (wid * 2 + i) * 1024;
            gload_lds16(Ah + offA, AsH + ldsOff);
            gload_lds16(Al + offA, AsL + ldsOff);
            gload_lds16(Wh + offW, BsH + ldsOff);
            gload_lds16(Wl + offW, BsL + ldsOff);
        }
        __syncthreads();

        short8 ah[4], al[4], bh[4], bl[4];
#pragma unroll
        for (int mi = 0; mi < 4; ++mi) {
            int r = wm * 64 + mi * 16 + fr;
            int o = r * 64 + ((fs ^ (r & 3)) << 4);
            ah[mi] = *reinterpret_cast<const short8*>(AsH + o);
            al[mi] = *reinterpret_cast<const short8*>(AsL + o);
        }
#pragma unroll
        for (int ni = 0; ni < 4; ++ni) {
            int c = wn * 64 + ni * 16 + fr;
            int o = c * 64 + ((fs ^ (c & 3)) << 4);
            bh[ni] = *reinterpret_cast<const short8*>(BsH + o);
            bl[ni] = *reinterpret_cast<const short8*>(BsL + o);
        }
#pragma unroll
        for (int mi = 0; mi < 4; ++mi)
#pragma unroll
            for (int ni = 0; ni < 4; ++ni)
                acc[mi][ni] = __builtin_amdgcn_mfma_f32_16x16x32_bf16(
                    ah[mi], bh[ni], acc[mi][ni], 0, 0, 0);
#pragma unroll
        for (int mi = 0; mi < 4; ++mi)
#pragma unroll
            for (int ni = 0; ni < 4; ++ni)
                acc[mi][ni] = __builtin_amdgcn_mfma_f32_16x16x32_bf16(
                    ah[mi], bl[ni], acc[mi][ni], 0, 0, 0);
#pragma unroll
        for (int mi = 0; mi < 4; ++mi)
#pragma unroll
            for (int ni = 0; ni < 4; ++ni)
                acc[mi][ni] = __builtin_amdgcn_mfma_f32_16x16x32_bf16(
                    al[mi], bh[ni], acc[mi][ni], 0, 0, 0);
    }

    float bv[4];
#pragma unroll
    for (int ni = 0; ni < 4; ++ni)
        bv[ni] = bias ? bias[bcol + wn * 64 + ni * 16 + fr] : 0.f;

#pragma unroll
    for (int mi = 0; mi < 4; ++mi) {
#pragma unroll
        for (int reg = 0; reg < 4; ++reg) {
            int row = brow + wm * 64 + mi * 16 + fs * 4 + reg;
#pragma unroll
            for (int ni = 0; ni < 4; ++ni) {
                int col = bcol + wn * 64 + ni * 16 + fr;
                float v = acc[mi][ni][reg] + bv[ni];
                unsigned short h = f2bf(v);
                Ch[(size_t)row * N + col] = h;
                Cl[(size_t)row * N + col] = f2bf(v - bf2f(h));
            }
        }
    }
}

// ---------------------------------------------------------------------------
// Windowed split-bf16 logits, BM=128 (l) x BN=64 (s) for occupancy:
// active blocks ~= (len/64) * 16 * 4 ~= 512 (vs 256 at BN=128).
// Wave wid owns rows [wid*32, wid*32+32) x all 64 cols.
__global__ __launch_bounds__(256) void k_logits_split(
    const unsigned short* __restrict__ Th, const unsigned short* __restrict__ Tl,
    const unsigned short* __restrict__ Dh, const unsigned short* __restrict__ Dl,
    const int* __restrict__ qp, float* __restrict__ logits)
{
    const int b = blockIdx.z;
    const int start = qp[b], len = qp[b + 1] - start;
    const int bcol = blockIdx.x * 64;
    if (bcol >= len) return;
    const int brow = blockIdx.y * 128;

    __shared__ __align__(16) char AsH[8192], AsL[8192], BsH[4096], BsL[4096];

    const int tid = threadIdx.x;
    const int ln  = tid & 63;
    const int wid = tid >> 6;
    const int fr  = ln & 15, fs = ln >> 4;
    const int st  = ln & 3;

    const size_t abase = (size_t)b * LQ;

    f32x4 acc[2][4] = {};

    for (int k0 = 0; k0 < D_DIM; k0 += 32) {
        if (k0) __syncthreads();
        // A: 128 rows x 32 k, 2 plane pairs, 2 rounds
#pragma unroll
        for (int i = 0; i < 2; ++i) {
            int r  = wid * 32 + i * 16 + (ln >> 2);
            int kk = (st ^ (r & 3)) * 8;
            size_t offA = (abase + brow + r) * D_DIM + k0 + kk;
            int ldsOff = (wid * 2 + i) * 1024;
            gload_lds16(Th + offA, AsH + ldsOff);
            gload_lds16(Tl + offA, AsL + ldsOff);
        }
        // B: 64 rows x 32 k, 1 round
        {
            int rb = wid * 16 + (ln >> 2);
            int kk = (st ^ (rb & 3)) * 8;
            int wr = start + bcol + rb; if (wr > NQ - 1) wr = NQ - 1;
            size_t offW = (size_t)wr * D_DIM + k0 + kk;
            gload_lds16(Dh + offW, BsH + wid * 1024);
            gload_lds16(Dl + offW, BsL + wid * 1024);
        }
        __syncthreads();

        short8 ah[2], al[2], bh[4], bl[4];
#pragma unroll
        for (int mi = 0; mi < 2; ++mi) {
            int r = wid * 32 + mi * 16 + fr;
            int o = r * 64 + ((fs ^ (r & 3)) << 4);
            ah[mi] = *reinterpret_cast<const short8*>(AsH + o);
            al[mi] = *reinterpret_cast<const short8*>(AsL + o);
        }
#pragma unroll
        for (int ni = 0; ni < 4; ++ni) {
            int c = ni * 16 + fr;
            int o = c * 64 + ((fs ^ (c & 3)) << 4);
            bh[ni] = *reinterpret_cast<const short8*>(BsH + o);
            bl[ni] = *reinterpret_cast<const short8*>(BsL + o);
        }
#pragma unroll
        for (int mi = 0; mi < 2; ++mi)
#pragma unroll
            for (int ni = 0; ni < 4; ++ni)
                acc[mi][ni] = __builtin_amdgcn_mfma_f32_16x16x32_bf16(
                    ah[mi], bh[ni], acc[mi][ni], 0, 0, 0);
#pragma unroll
        for (int mi = 0; mi < 2; ++mi)
#pragma unroll
            for (int ni = 0; ni < 4; ++ni)
                acc[mi][ni] = __builtin_amdgcn_mfma_f32_16x16x32_bf16(
                    ah[mi], bl[ni], acc[mi][ni], 0, 0, 0);
#pragma unroll
        for (int mi = 0; mi < 2; ++mi)
#pragma unroll
            for (int ni = 0; ni < 4; ++ni)
                acc[mi][ni] = __builtin_amdgcn_mfma_f32_16x16x32_bf16(
                    al[mi], bh[ni], acc[mi][ni], 0, 0, 0);
    }

#pragma unroll
    for (int mi = 0; mi < 2; ++mi) {
#pragma unroll
        for (int reg = 0; reg < 4; ++reg) {
            size_t row = (size_t)b * LQ + brow + wid * 32 + mi * 16 + fs * 4 + reg;
#pragma unroll
            for (int ni = 0; ni < 4; ++ni) {
                int col = bcol + ni * 16 + fr;
                logits[row * SMAX + col] = acc[mi][ni][reg];
            }
        }
    }
}

// ---------------------------------------------------------------------------
// Plain bf16 GEMM, fp32 out (final projection).
__global__ __launch_bounds__(256) void k_gemm_bf16_f32out(
    const unsigned short* __restrict__ A, const unsigned short* __restrict__ W,
    const float* __restrict__ bias, float* __restrict__ C,
    int M, int N, int K)
{
    __shared__ __align__(16) char As[8192], Bs[8192];

    const int tid = threadIdx.x;
    const int ln  = tid & 63;
    const int wid = tid >> 6;
    const int wm  = wid >> 1, wn = wid & 1;
    const int fr  = ln & 15, fs = ln >> 4;
    const int brow = blockIdx.y * 128;
    const int bcol = blockIdx.x * 128;
    const int st   = ln & 3;

    f32x4 acc[4][4] = {};

    for (int k0 = 0; k0 < K; k0 += 32) {
        if (k0) __syncthreads();
#pragma unroll
        for (int i = 0; i < 2; ++i) {
            int r  = wid * 32 + i * 16 + (ln >> 2);
            int kk = (st ^ (r & 3)) * 8;
            gload_lds16(A + (size_t)(brow + r) * K + k0 + kk, As + (wid * 2 + i) * 1024);
            gload_lds16(W + (size_t)(bcol + r) * K + k0 + kk, Bs + (wid * 2 + i) * 1024);
        }
        __syncthreads();

        short8 a[4], b[4];
#pragma unroll
        for (int mi = 0; mi < 4; ++mi) {
            int r = wm * 64 + mi * 16 + fr;
            a[mi] = *reinterpret_cast<const short8*>(As + r * 64 + ((fs ^ (r & 3)) << 4));
        }
#pragma unroll
        for (int ni = 0; ni < 4; ++ni) {
            int c = wn * 64 + ni * 16 + fr;
            b[ni] = *reinterpret_cast<const short8*>(Bs + c * 64 + ((fs ^ (c & 3)) << 4));
        }
#pragma unroll
        for (int mi = 0; mi < 4; ++mi)
#pragma unroll
            for (int ni = 0; ni < 4; ++ni)
                acc[mi][ni] = __builtin_amdgcn_mfma_f32_16x16x32_bf16(
                    a[mi], b[ni], acc[mi][ni], 0, 0, 0);
    }

    float bv[4];
#pragma unroll
    for (int ni = 0; ni < 4; ++ni)
        bv[ni] = bias ? bias[bcol + wn * 64 + ni * 16 + fr] : 0.f;

#pragma unroll
    for (int mi = 0; mi < 4; ++mi) {
#pragma unroll
        for (int reg = 0; reg < 4; ++reg) {
            int row = brow + wm * 64 + mi * 16 + fs * 4 + reg;
#pragma unroll
            for (int ni = 0; ni < 4; ++ni) {
                int col = bcol + wn * 64 + ni * 16 + fr;
                C[(size_t)row * N + col] = acc[mi][ni][reg] + bv[ni];
            }
        }
    }
}

// ---------------------------------------------------------------------------
// Wave-per-row top-8 + softmax + mix. No barriers, no LDS.
// Lane ln holds 16 logits in regs; 8 rounds of {local argmax over 16 +
// 6-step butterfly argmax (lowest-index tiebreak) + reg invalidate}.
__global__ __launch_bounds__(256) void k_topk_mix_wave(
    const float* __restrict__ logits, const float* __restrict__ Z,
    const int* __restrict__ qp, unsigned short* __restrict__ mix)
{
    const int ln  = threadIdx.x & 63;
    const int row = blockIdx.x * 4 + (threadIdx.x >> 6);   // (b*L + l)
    const int b   = row >> 11;                              // L = 2048
    const int start = qp[b], len = qp[b + 1] - start;

    const float* lrow = logits + (size_t)row * SMAX;

    // load 16 values, coalesced float4; element j's global s-index:
    //   s(j) = (j>>2)*256 + ln*4 + (j&3)
    float v[16];
#pragma unroll
    for (int c = 0; c < 4; ++c) {
        float4 q = reinterpret_cast<const float4*>(lrow)[c * 64 + ln];
        int s0 = c * 256 + ln * 4;
        v[c * 4 + 0] = (s0 + 0 < len) ? q.x : -INFINITY;
        v[c * 4 + 1] = (s0 + 1 < len) ? q.y : -INFINITY;
        v[c * 4 + 2] = (s0 + 2 < len) ? q.z : -INFINITY;
        v[c * 4 + 3] = (s0 + 3 < len) ? q.w : -INFINITY;
    }

    float wv[TOPK]; int wi[TOPK];
#pragma unroll
    for (int it = 0; it < TOPK; ++it) {
        // local argmax over 16 regs
        float bv = v[0]; int bj = 0;
#pragma unroll
        for (int j = 1; j < 16; ++j)
            if (v[j] > bv) { bv = v[j]; bj = j; }
        int gidx = (bj >> 2) * 256 + ln * 4 + (bj & 3);
        // wave butterfly argmax, lowest global index wins ties
        float cv = bv; int ci = gidx;
#pragma unroll
        for (int off = 32; off > 0; off >>= 1) {
            float ov = __shfl_xor(cv, off);
            int   oi = __shfl_xor(ci, off);
            if (ov > cv || (ov == cv && oi < ci)) { cv = ov; ci = oi; }
        }
        wv[it] = cv; wi[it] = ci;
        // invalidate winner (compile-time reg indices; rule #20)
#pragma unroll
        for (int j = 0; j < 16; ++j) {
            int sj = (j >> 2) * 256 + ln * 4 + (j & 3);
            if (sj == ci) v[j] = -INFINITY;
        }
    }

    // softmax over the 8 (wv[0] is the max)
    float m = wv[0], denom = 0.f;
    float g[TOPK];
#pragma unroll
    for (int k = 0; k < TOPK; ++k) { g[k] = expf(wv[k] - m); denom += g[k]; }
    float inv = 1.f / denom;

    // mix: lane ln owns dims {c*256 + ln*4 .. +4} for c = 0..3
    float4 acc[4] = {{0,0,0,0},{0,0,0,0},{0,0,0,0},{0,0,0,0}};
#pragma unroll
    for (int k = 0; k < TOPK; ++k) {
        int si = wi[k] >= 0 ? wi[k] : 0;
        const float4* zr = reinterpret_cast<const float4*>(Z + (size_t)(start + si) * D_DIM);
        float wgt = g[k] * inv;
#pragma unroll
        for (int c = 0; c < 4; ++c) {
            float4 z = zr[c * 64 + ln];
            acc[c].x = fmaf(wgt, z.x, acc[c].x);
            acc[c].y = fmaf(wgt, z.y, acc[c].y);
            acc[c].z = fmaf(wgt, z.z, acc[c].z);
            acc[c].w = fmaf(wgt, z.w, acc[c].w);
        }
    }
    unsigned short* mrow = mix + (size_t)row * D_DIM;
#pragma unroll
    for (int c = 0; c < 4; ++c) {
        ushort4v o;
        o[0] = f2bf(acc[c].x); o[1] = f2bf(acc[c].y);
        o[2] = f2bf(acc[c].z); o[3] = f2bf(acc[c].w);
        *reinterpret_cast<ushort4v*>(mrow + (c * 64 + ln) * 4) = o;
    }
}

// ---------------------------------------------------------------------------
extern "C" void kernel_launch(void* const* d_in, const int* in_sizes, int n_in,
                              void* d_out, int out_size, void* d_ws, size_t ws_size,
                              hipStream_t stream) {
    const float* token_states = (const float*)d_in[0];
    const float* Z_sets       = (const float*)d_in[1];
    const float* desc_q       = (const float*)d_in[2];
    const int*   q_raw        = (const int*)d_in[3];
    const float* Wg_w  = (const float*)d_in[4];
    const float* Wg_b  = (const float*)d_in[5];
    const float* Wd_w  = (const float*)d_in[6];
    const float* Wd_b  = (const float*)d_in[7];
    const float* out_w = (const float*)d_in[8];
    const float* out_b = (const float*)d_in[9];
    float* out = (float*)d_out;

    const size_t NTOK = (size_t)BQ * LQ * D_DIM;
    const size_t NDES = (size_t)NQ * D_DIM;
    const size_t NW   = (size_t)D_DIM * D_DIM;

    char* ws = (char*)d_ws;
    int* qp = (int*)ws;
    unsigned short* tokenH = (unsigned short*)(ws + 256);
    unsigned short* tokenL = tokenH + NTOK;
    unsigned short* descH  = tokenL + NTOK;
    unsigned short* descL  = descH + NDES;
    unsigned short* wgH    = descL + NDES;
    unsigned short* wgL    = wgH + NW;
    unsigned short* wdH    = wgL + NW;
    unsigned short* wdL    = wdH + NW;
    unsigned short* owb    = wdL + NW;
    unsigned short* TprojH = owb + NW;
    unsigned short* TprojL = TprojH + NTOK;
    unsigned short* DprojH = TprojL + NTOK;
    unsigned short* DprojL = DprojH + NDES;
    float* logit          = (float*)tokenH;   // alias: token planes dead after Tproj GEMM
    unsigned short* mixb  = TprojH;           // alias: TprojH dead after logits GEMM

    k_convert_qptrs<<<1, 64, 0, stream>>>(q_raw, qp);

    k_cvt_split<<<NTOK / 2048, 256, 0, stream>>>(token_states, tokenH, tokenL, (int)NTOK);
    k_cvt_split<<<NDES / 2048, 256, 0, stream>>>(desc_q, descH, descL, (int)NDES);
    k_cvt_split<<<NW / 2048, 256, 0, stream>>>(Wg_w, wgH, wgL, (int)NW);
    k_cvt_split<<<NW / 2048, 256, 0, stream>>>(Wd_w, wdH, wdL, (int)NW);
    k_cvt_bf16<<<NW / 2048, 256, 0, stream>>>(out_w, owb, (int)NW);

    // Tproj = token @ Wg^T + b  (split out)
    k_gemm_split<<<dim3(D_DIM / 128, (BQ * LQ) / 128), 256, 0, stream>>>(
        tokenH, tokenL, wgH, wgL, Wg_b, TprojH, TprojL, BQ * LQ, D_DIM, D_DIM);

    // Dproj = desc @ Wd^T + b  (split out)
    k_gemm_split<<<dim3(D_DIM / 128, NQ / 128), 256, 0, stream>>>(
        descH, descL, wdH, wdL, Wd_b, DprojH, DprojL, NQ, D_DIM, D_DIM);

    // logits (fp32, windowed; overwrites token planes)
    k_logits_split<<<dim3(SMAX / 64, LQ / 128, BQ), 256, 0, stream>>>(
        TprojH, TprojL, DprojH, DprojL, qp, logit);

    // top-8 + softmax + Z mix (bf16; overwrites TprojH)
    k_topk_mix_wave<<<(BQ * LQ) / 4, 256, 0, stream>>>(logit, Z_sets, qp, mixb);

    // out = mix @ out_w^T + b (fp32)
    k_gemm_bf16_f32out<<<dim3(D_DIM / 128, (BQ * LQ) / 128), 256, 0, stream>>>(
        mixb, owb, out_b, out, BQ * LQ, D_DIM, D_DIM);
}